// Round 22
// baseline (87.519 us; speedup 1.0000x reference)
//
#include <hip/hip_runtime.h>
#include <math.h>

#define TB 16
#define TL 8192
#define TC 64

constexpr float INV_BL = 1.0f / (16.0f * 8192.0f);
constexpr float EPSV = 1e-5f;
constexpr float INV_SQRT_H = 0.17677669529663687f; // 1/sqrt(32)

// workspace offsets (floats) — ws is 256 MiB
#define WS_G      0        /* [16][64][64] */
#define WS_SX     65536    /* [16][64] */
#define WS_STATS  66560    /* s1[64] d1[64] s2[64] d2[64] */
#define WS_M      66816    /* [16][64][64] */
#define WS_N      132352   /* [16][64][64] */
#define WS_S1T    197888   /* [16][64][256] -> ends 460032 */
#define WS_V1P    460032   /* bf16x2: [16][16jp][32c2][256i] uints -> ends 2557184 */
#define WS_GPART  4654336  /* [16][32][4096] -> ends 6751488 */
#define WS_SXPART 6751488  /* [16][32][64] -> ends 6784256 */
#define WS_MPART  6784256  /* [16][16][4096] -> ends 7832832 */
#define WS_WKT    7832832  /* wk^T [64][256] -> ends 7849216 */

typedef __attribute__((ext_vector_type(8))) short short8v;  // 8 bf16 (4 VGPRs)
typedef __attribute__((ext_vector_type(4))) float f32x4;    // MFMA C/D

__device__ __forceinline__ ushort bf16rne(float f){
  uint u = __float_as_uint(f);
  u += 0x7FFF + ((u >> 16) & 1);
  return (ushort)(u >> 16);
}

__device__ __forceinline__ int fraddr(int ch, int g){
  return ch*128 + 8*(g ^ (ch & 7));
}

// ---------------- K1 v8: MFMA Gram, 2 subtiles/block with T14 prefetch (R21-proven) ----------------
__global__ __launch_bounds__(256) void k1_gram(const float* __restrict__ x,
                                               float* __restrict__ ws){
  __shared__ ushort Xh[64*128];
  __shared__ ushort Xl[64*128];
  const int b = blockIdx.y, chunk = blockIdx.x;
  const int t = threadIdx.x;
  const int lane = t & 63;
  const int w = __builtin_amdgcn_readfirstlane(t >> 6);  // wave 0..3
  const float* xb = x + (size_t)b*TC*TL + (size_t)chunk*256;
  const int ch = t >> 2, q = t & 3;
  float sx = 0.f;
  const int rA = w*16 + (lane & 15);
  const int rB = lane & 15;
  const int gq = lane >> 4;
  f32x4 acc0={0.f,0.f,0.f,0.f}, acc1={0.f,0.f,0.f,0.f},
        acc2={0.f,0.f,0.f,0.f}, acc3={0.f,0.f,0.f,0.f};
  float4 rgv[8];
  #pragma unroll
  for (int gg=0; gg<4; ++gg){
    rgv[2*gg]   = *(const float4*)(xb + ch*TL + q*32 + 8*gg);
    rgv[2*gg+1] = *(const float4*)(xb + ch*TL + q*32 + 8*gg + 4);
  }
  #pragma unroll
  for (int gg=0; gg<4; ++gg){
    const float4 v0 = rgv[2*gg], v1 = rgv[2*gg+1];
    const float ff[8] = {v0.x,v0.y,v0.z,v0.w,v1.x,v1.y,v1.z,v1.w};
    union { short8v v; ushort u[8]; } hh, ll;
    #pragma unroll
    for (int i=0;i<8;++i){
      sx += ff[i];
      const ushort hv = bf16rne(ff[i]);
      hh.u[i] = hv;
      ll.u[i] = bf16rne(ff[i] - __uint_as_float(((uint)hv)<<16));
    }
    const int g = q*4 + gg;
    const int wa = ch*128 + 8*(g ^ (ch & 7));
    *(short8v*)&Xh[wa] = hh.v;
    *(short8v*)&Xl[wa] = ll.v;
  }
  __syncthreads();
  float4 rg2[8];
  #pragma unroll
  for (int gg=0; gg<4; ++gg){
    rg2[2*gg]   = *(const float4*)(xb + ch*TL + 128 + q*32 + 8*gg);
    rg2[2*gg+1] = *(const float4*)(xb + ch*TL + 128 + q*32 + 8*gg + 4);
  }
  #pragma unroll
  for (int kk=0; kk<4; ++kk){
    const int g = kk*4 + gq;
    const short8v Ah = *(const short8v*)&Xh[fraddr(rA, g)];
    const short8v Al = *(const short8v*)&Xl[fraddr(rA, g)];
    const short8v Bh0 = *(const short8v*)&Xh[fraddr(rB,      g)];
    const short8v Bl0 = *(const short8v*)&Xl[fraddr(rB,      g)];
    const short8v Bh1 = *(const short8v*)&Xh[fraddr(rB + 16, g)];
    const short8v Bl1 = *(const short8v*)&Xl[fraddr(rB + 16, g)];
    const short8v Bh2 = *(const short8v*)&Xh[fraddr(rB + 32, g)];
    const short8v Bl2 = *(const short8v*)&Xl[fraddr(rB + 32, g)];
    const short8v Bh3 = *(const short8v*)&Xh[fraddr(rB + 48, g)];
    const short8v Bl3 = *(const short8v*)&Xl[fraddr(rB + 48, g)];
    acc0 = __builtin_amdgcn_mfma_f32_16x16x32_bf16(Ah, Bh0, acc0, 0, 0, 0);
    acc0 = __builtin_amdgcn_mfma_f32_16x16x32_bf16(Ah, Bl0, acc0, 0, 0, 0);
    acc0 = __builtin_amdgcn_mfma_f32_16x16x32_bf16(Al, Bh0, acc0, 0, 0, 0);
    acc0 = __builtin_amdgcn_mfma_f32_16x16x32_bf16(Al, Bl0, acc0, 0, 0, 0);
    acc1 = __builtin_amdgcn_mfma_f32_16x16x32_bf16(Ah, Bh1, acc1, 0, 0, 0);
    acc1 = __builtin_amdgcn_mfma_f32_16x16x32_bf16(Ah, Bl1, acc1, 0, 0, 0);
    acc1 = __builtin_amdgcn_mfma_f32_16x16x32_bf16(Al, Bh1, acc1, 0, 0, 0);
    acc1 = __builtin_amdgcn_mfma_f32_16x16x32_bf16(Al, Bl1, acc1, 0, 0, 0);
    acc2 = __builtin_amdgcn_mfma_f32_16x16x32_bf16(Ah, Bh2, acc2, 0, 0, 0);
    acc2 = __builtin_amdgcn_mfma_f32_16x16x32_bf16(Ah, Bl2, acc2, 0, 0, 0);
    acc2 = __builtin_amdgcn_mfma_f32_16x16x32_bf16(Al, Bh2, acc2, 0, 0, 0);
    acc2 = __builtin_amdgcn_mfma_f32_16x16x32_bf16(Al, Bl2, acc2, 0, 0, 0);
    acc3 = __builtin_amdgcn_mfma_f32_16x16x32_bf16(Ah, Bh3, acc3, 0, 0, 0);
    acc3 = __builtin_amdgcn_mfma_f32_16x16x32_bf16(Ah, Bl3, acc3, 0, 0, 0);
    acc3 = __builtin_amdgcn_mfma_f32_16x16x32_bf16(Al, Bh3, acc3, 0, 0, 0);
    acc3 = __builtin_amdgcn_mfma_f32_16x16x32_bf16(Al, Bl3, acc3, 0, 0, 0);
  }
  __syncthreads();
  #pragma unroll
  for (int gg=0; gg<4; ++gg){
    const float4 v0 = rg2[2*gg], v1 = rg2[2*gg+1];
    const float ff[8] = {v0.x,v0.y,v0.z,v0.w,v1.x,v1.y,v1.z,v1.w};
    union { short8v v; ushort u[8]; } hh, ll;
    #pragma unroll
    for (int i=0;i<8;++i){
      sx += ff[i];
      const ushort hv = bf16rne(ff[i]);
      hh.u[i] = hv;
      ll.u[i] = bf16rne(ff[i] - __uint_as_float(((uint)hv)<<16));
    }
    const int g = q*4 + gg;
    const int wa = ch*128 + 8*(g ^ (ch & 7));
    *(short8v*)&Xh[wa] = hh.v;
    *(short8v*)&Xl[wa] = ll.v;
  }
  __syncthreads();
  #pragma unroll
  for (int kk=0; kk<4; ++kk){
    const int g = kk*4 + gq;
    const short8v Ah = *(const short8v*)&Xh[fraddr(rA, g)];
    const short8v Al = *(const short8v*)&Xl[fraddr(rA, g)];
    const short8v Bh0 = *(const short8v*)&Xh[fraddr(rB,      g)];
    const short8v Bl0 = *(const short8v*)&Xl[fraddr(rB,      g)];
    const short8v Bh1 = *(const short8v*)&Xh[fraddr(rB + 16, g)];
    const short8v Bl1 = *(const short8v*)&Xl[fraddr(rB + 16, g)];
    const short8v Bh2 = *(const short8v*)&Xh[fraddr(rB + 32, g)];
    const short8v Bl2 = *(const short8v*)&Xl[fraddr(rB + 32, g)];
    const short8v Bh3 = *(const short8v*)&Xh[fraddr(rB + 48, g)];
    const short8v Bl3 = *(const short8v*)&Xl[fraddr(rB + 48, g)];
    acc0 = __builtin_amdgcn_mfma_f32_16x16x32_bf16(Ah, Bh0, acc0, 0, 0, 0);
    acc0 = __builtin_amdgcn_mfma_f32_16x16x32_bf16(Ah, Bl0, acc0, 0, 0, 0);
    acc0 = __builtin_amdgcn_mfma_f32_16x16x32_bf16(Al, Bh0, acc0, 0, 0, 0);
    acc0 = __builtin_amdgcn_mfma_f32_16x16x32_bf16(Al, Bl0, acc0, 0, 0, 0);
    acc1 = __builtin_amdgcn_mfma_f32_16x16x32_bf16(Ah, Bh1, acc1, 0, 0, 0);
    acc1 = __builtin_amdgcn_mfma_f32_16x16x32_bf16(Ah, Bl1, acc1, 0, 0, 0);
    acc1 = __builtin_amdgcn_mfma_f32_16x16x32_bf16(Al, Bh1, acc1, 0, 0, 0);
    acc1 = __builtin_amdgcn_mfma_f32_16x16x32_bf16(Al, Bl1, acc1, 0, 0, 0);
    acc2 = __builtin_amdgcn_mfma_f32_16x16x32_bf16(Ah, Bh2, acc2, 0, 0, 0);
    acc2 = __builtin_amdgcn_mfma_f32_16x16x32_bf16(Ah, Bl2, acc2, 0, 0, 0);
    acc2 = __builtin_amdgcn_mfma_f32_16x16x32_bf16(Al, Bh2, acc2, 0, 0, 0);
    acc2 = __builtin_amdgcn_mfma_f32_16x16x32_bf16(Al, Bl2, acc2, 0, 0, 0);
    acc3 = __builtin_amdgcn_mfma_f32_16x16x32_bf16(Ah, Bh3, acc3, 0, 0, 0);
    acc3 = __builtin_amdgcn_mfma_f32_16x16x32_bf16(Ah, Bl3, acc3, 0, 0, 0);
    acc3 = __builtin_amdgcn_mfma_f32_16x16x32_bf16(Al, Bh3, acc3, 0, 0, 0);
    acc3 = __builtin_amdgcn_mfma_f32_16x16x32_bf16(Al, Bl3, acc3, 0, 0, 0);
  }
  float* Gp = ws + WS_GPART + (size_t)(b*32 + chunk)*4096;
  const int col = lane & 15, rq = lane >> 4;
  #pragma unroll
  for (int r=0;r<4;++r){
    const int row = (w*16 + rq*4 + r)*64;
    Gp[row +  0 + col] = acc0[r];
    Gp[row + 16 + col] = acc1[r];
    Gp[row + 32 + col] = acc2[r];
    Gp[row + 48 + col] = acc3[r];
  }
  sx += __shfl_xor(sx, 1, 4);
  sx += __shfl_xor(sx, 2, 4);
  if (q == 0){
    ws[WS_SXPART + (b*32+chunk)*64 + ch] = sx;
  }
}

// ---------------- KA1: coalesced G/Sx reduce (32 partials) + STATS zero + wk^T ----------------
__global__ __launch_bounds__(256) void kA1(const float* __restrict__ wk,
                                           float* __restrict__ ws){
  const int p = blockIdx.x, b = blockIdx.y;
  const int t = threadIdx.x;
  const float* Gp = ws + WS_GPART + (size_t)b*32*4096 + p*256 + t;
  float s = 0.f;
  #pragma unroll 8
  for (int ch=0; ch<32; ++ch) s += Gp[(size_t)ch*4096];
  ws[WS_G + b*4096 + p*256 + t] = s;
  if (p==0 && t<64){
    float sv = 0.f;
    #pragma unroll 8
    for (int ch=0; ch<32; ++ch) sv += ws[WS_SXPART + (b*32+ch)*64 + t];
    ws[WS_SX + b*64 + t] = sv;
  }
  if (p==0 && b==0) ws[WS_STATS + t] = 0.f;
  if (b==0){
    const int j = 16*p + (t>>4), k0 = (t&15)*4;
    const float4 v = *(const float4*)(wk + j*64 + k0);
    ws[WS_WKT + (k0+0)*256 + j] = v.x;
    ws[WS_WKT + (k0+1)*256 + j] = v.y;
    ws[WS_WKT + (k0+2)*256 + j] = v.z;
    ws[WS_WKT + (k0+3)*256 + j] = v.w;
  }
}

// ---------------- KA2 v2: S1^T = (wq G)^T, 256 blocks (R19-proven) ----------------
__global__ __launch_bounds__(256) void kA2(const float* __restrict__ wq,
                                           float* __restrict__ ws){
  __shared__ float Gt[64*68];
  const int b = blockIdx.y, iblk = blockIdx.x;
  const int t = threadIdx.x;
  const float* G = ws + WS_G + b*4096;
  #pragma unroll
  for (int r=0;r<4;++r){
    const int idx = r*1024 + t*4;
    *(float4*)&Gt[(idx>>6)*68 + (idx&63)] = *(const float4*)(G + idx);
  }
  __syncthreads();
  const int il = t>>4, cq = t&15;
  const int i = iblk*16 + il;
  const float* wqr = wq + i*64;
  float4 a0={0,0,0,0};
  #pragma unroll 8
  for (int k=0;k<64;++k){
    const float a = wqr[k];
    const float4 g0 = *(const float4*)&Gt[k*68 + cq*4];
    a0.x=fmaf(a,g0.x,a0.x); a0.y=fmaf(a,g0.y,a0.y); a0.z=fmaf(a,g0.z,a0.z); a0.w=fmaf(a,g0.w,a0.w);
  }
  float* S1T = ws + WS_S1T + b*16384;
  S1T[(cq*4+0)*256 + i]=a0.x;
  S1T[(cq*4+1)*256 + i]=a0.y;
  S1T[(cq*4+2)*256 + i]=a0.z;
  S1T[(cq*4+3)*256 + i]=a0.w;
}

// ---------------- KB12 v3: scores + softmax + PV packed bf16x2 [c2][row] ----------------
__global__ __launch_bounds__(256) void kb12(const float* __restrict__ wv,
                                            float* __restrict__ ws){
  __shared__ float scl[256*17];
  __shared__ float pstat[256];
  __shared__ float fstat[32];
  const int b = blockIdx.y, jp = blockIdx.x;
  const int j0 = jp*16;
  const int t = threadIdx.x;
  const float* S1Tb = ws + WS_S1T + b*16384;
  const float* wkT = ws + WS_WKT;
  float sc[16];
  #pragma unroll
  for (int jj=0;jj<16;++jj) sc[jj]=0.f;
  #pragma unroll 4
  for (int k=0;k<64;++k){
    const float s1 = S1Tb[k*256 + t];
    const float4 w0 = *(const float4*)(wkT + k*256 + j0);
    const float4 w1 = *(const float4*)(wkT + k*256 + j0 + 4);
    const float4 w2 = *(const float4*)(wkT + k*256 + j0 + 8);
    const float4 w3 = *(const float4*)(wkT + k*256 + j0 + 12);
    sc[ 0]=fmaf(w0.x,s1,sc[ 0]); sc[ 1]=fmaf(w0.y,s1,sc[ 1]); sc[ 2]=fmaf(w0.z,s1,sc[ 2]); sc[ 3]=fmaf(w0.w,s1,sc[ 3]);
    sc[ 4]=fmaf(w1.x,s1,sc[ 4]); sc[ 5]=fmaf(w1.y,s1,sc[ 5]); sc[ 6]=fmaf(w1.z,s1,sc[ 6]); sc[ 7]=fmaf(w1.w,s1,sc[ 7]);
    sc[ 8]=fmaf(w2.x,s1,sc[ 8]); sc[ 9]=fmaf(w2.y,s1,sc[ 9]); sc[10]=fmaf(w2.z,s1,sc[10]); sc[11]=fmaf(w2.w,s1,sc[11]);
    sc[12]=fmaf(w3.x,s1,sc[12]); sc[13]=fmaf(w3.y,s1,sc[13]); sc[14]=fmaf(w3.z,s1,sc[14]); sc[15]=fmaf(w3.w,s1,sc[15]);
  }
  #pragma unroll
  for (int jj=0;jj<16;++jj) scl[t*17+jj] = sc[jj];
  __syncthreads();
  const int col = t&15, ig = t>>4;
  {
    float m = -3.0e38f;
    #pragma unroll
    for (int q=0;q<16;++q) m = fmaxf(m, scl[(ig*16+q)*17 + col]);
    pstat[ig*16+col] = m;
  }
  __syncthreads();
  if (t<16){
    float m = -3.0e38f;
    #pragma unroll
    for (int q=0;q<16;++q) m = fmaxf(m, pstat[q*16+t]);
    fstat[t] = m;
  }
  __syncthreads();
  {
    const float mj = fstat[col];
    float s = 0.f;
    #pragma unroll
    for (int q=0;q<16;++q) s += __expf(scl[(ig*16+q)*17 + col] - mj);
    pstat[ig*16+col] = s;
  }
  __syncthreads();
  if (t<16){
    float s = 0.f;
    #pragma unroll
    for (int q=0;q<16;++q) s += pstat[q*16+t];
    fstat[16+t] = 1.f/s;
  }
  __syncthreads();
  #pragma unroll
  for (int jj=0;jj<16;++jj)
    sc[jj] = __expf(sc[jj] - fstat[jj]) * fstat[16+jj];
  // PV: row t; pack pairs (c even = low bf16) -> [c2][row] uints, coalesced per c2 column
  uint* Vp = (uint*)(ws + WS_V1P) + (size_t)(b*16 + jp)*8192;
  #pragma unroll
  for (int cb=0; cb<4; ++cb){
    float acc[16];
    #pragma unroll
    for (int cc=0;cc<16;++cc) acc[cc]=0.f;
    #pragma unroll
    for (int jj=0;jj<16;++jj){
      const float p = sc[jj];
      const float* wvr = wv + (j0+jj)*64 + cb*16;
      #pragma unroll
      for (int cc=0;cc<16;++cc)
        acc[cc] = fmaf(p, wvr[cc], acc[cc]);
    }
    #pragma unroll
    for (int g=0; g<8; ++g){
      const uint lo = (uint)bf16rne(acc[2*g]);
      const uint hi = (uint)bf16rne(acc[2*g+1]);
      Vp[(cb*8 + g)*256 + t] = (hi << 16) | lo;
    }
  }
}

// ---------------- KC v4: sum bf16x2 V1 partials + M K-partials ----------------
__global__ __launch_bounds__(256) void kc_mpart(const float* __restrict__ wc,
                                                float* __restrict__ ws){
  __shared__ float V1l[16*65];
  const int b = blockIdx.y, kq = blockIdx.x;
  const int t = threadIdx.x;
  // 512 uints: thread handles 2. e: c2 = e>>4 (0..31), il = e&15
  #pragma unroll
  for (int r=0;r<2;++r){
    const int e = t + 256*r;
    const int c2 = e >> 4, il = e & 15;
    const uint* Vp = (const uint*)(ws + WS_V1P) + (size_t)b*16*8192 + c2*256 + kq*16 + il;
    float s0 = 0.f, s1 = 0.f;
    #pragma unroll
    for (int jp=0;jp<16;++jp){
      const uint u = Vp[jp*8192];
      s0 += __uint_as_float(u << 16);
      s1 += __uint_as_float(u & 0xFFFF0000u);
    }
    V1l[il*65 + 2*c2]     = s0 * INV_SQRT_H;
    V1l[il*65 + 2*c2 + 1] = s1 * INV_SQRT_H;
  }
  __syncthreads();
  const int c = t & 63;
  const int og = __builtin_amdgcn_readfirstlane(t >> 6);
  float acc[16];
  #pragma unroll
  for (int oo=0;oo<16;++oo) acc[oo]=0.f;
  #pragma unroll
  for (int il=0; il<16; ++il){
    const float v = V1l[il*65 + c];
    const float* wcr = wc + (og*16)*256 + kq*16 + il;
    #pragma unroll
    for (int oo=0;oo<16;++oo)
      acc[oo] = fmaf(wcr[oo*256], v, acc[oo]);
  }
  float* Mp = ws + WS_MPART + (size_t)(b*16 + kq)*4096;
  #pragma unroll
  for (int oo=0;oo<16;++oo)
    Mp[(og*16+oo)*64 + c] = acc[oo];
}

// ---------------- KD v2: M rows + BN1 stats (R12-proven) ----------------
__global__ __launch_bounds__(256) void kd_stats1(float* __restrict__ ws){
  __shared__ float Msub[4*65];
  __shared__ float Gl[64*67];
  __shared__ float Sxl[64];
  const int b = blockIdx.y, oq = blockIdx.x;
  const int t = threadIdx.x;
  const int o = t >> 6, lane = t & 63;
  const int row = oq*4 + o;
  {
    const float* Mp = ws + WS_MPART + (size_t)b*16*4096 + row*64 + lane;
    float s = 0.f;
    #pragma unroll
    for (int kq=0;kq<16;++kq) s += Mp[kq*4096];
    ws[WS_M + b*4096 + row*64 + lane] = s;
    Msub[o*65 + lane] = s;
  }
  #pragma unroll
  for (int r=0;r<16;++r){
    const int e = t + 256*r;
    Gl[(e>>6)*67 + (e&63)] = ws[WS_G + b*4096 + e];
  }
  if (t<64) Sxl[t] = ws[WS_SX + b*64 + t];
  __syncthreads();
  float sk = 0.f;
  #pragma unroll 4
  for (int c=0;c<64;++c) sk = fmaf(Gl[lane*67+c], Msub[o*65+c], sk);
  float d = Msub[o*65 + lane] * sk;
  float s1 = Msub[o*65 + lane] * Sxl[lane];
  #pragma unroll
  for (int off=1; off<64; off<<=1){
    d  += __shfl_xor(d,  off);
    s1 += __shfl_xor(s1, off);
  }
  if (lane==0){
    atomicAdd(&ws[WS_STATS + row], s1);
    atomicAdd(&ws[WS_STATS + 64 + row], d);
  }
}

// ---------------- KE v2: N rows + BN2 stats (R12-proven) ----------------
__global__ __launch_bounds__(256) void ke_n_stats2(const float* __restrict__ wl,
                                                   const float* __restrict__ g1,
                                                   float* __restrict__ ws){
  __shared__ float Ml[64*65];
  __shared__ float Gl[64*67];
  __shared__ float Nsub[4*65];
  __shared__ float Sxl[64], a1l[64];
  const int b = blockIdx.y, oq = blockIdx.x;
  const int t = threadIdx.x;
  const int o = t >> 6, lane = t & 63;
  const int row = oq*4 + o;
  if (t<64){
    const float mean1 = ws[WS_STATS+t]*INV_BL;
    const float var1 = ws[WS_STATS+64+t]*INV_BL - mean1*mean1;
    a1l[t] = g1[t]*rsqrtf(var1 + EPSV);
    Sxl[t] = ws[WS_SX + b*64 + t];
  }
  #pragma unroll
  for (int r=0;r<16;++r){
    const int e = t + 256*r;
    Ml[(e>>6)*65 + (e&63)] = ws[WS_M + b*4096 + e];
    Gl[(e>>6)*67 + (e&63)] = ws[WS_G + b*4096 + e];
  }
  __syncthreads();
  float acc = 0.f;
  #pragma unroll 4
  for (int k=0;k<64;++k){
    const float wk_ = wl[row*64 + k] * a1l[k];
    acc = fmaf(wk_, Ml[k*65 + lane], acc);
  }
  const float nv = acc + wl[row*64 + lane];
  ws[WS_N + b*4096 + row*64 + lane] = nv;
  Nsub[o*65 + lane] = nv;
  __syncthreads();
  float sk = 0.f;
  #pragma unroll 4
  for (int c=0;c<64;++c) sk = fmaf(Gl[lane*67+c], Nsub[o*65+c], sk);
  float d = Nsub[o*65 + lane] * sk;
  float s2 = Nsub[o*65 + lane] * Sxl[lane];
  #pragma unroll
  for (int off=1; off<64; off<<=1){
    d  += __shfl_xor(d,  off);
    s2 += __shfl_xor(s2, off);
  }
  if (lane==0){
    atomicAdd(&ws[WS_STATS + 128 + row], s2);
    atomicAdd(&ws[WS_STATS + 192 + row], d);
  }
}

// ---------------- K3 v7: MFMA out-GEMM, 2 windows/block with T14 prefetch (R21-proven) ----------------
__global__ __launch_bounds__(512) void k3_out(const float* __restrict__ x,
                                              const float* __restrict__ g2,
                                              const float* __restrict__ b2,
                                              const float* __restrict__ ws,
                                              float* __restrict__ out){
  __shared__ ushort Xh[128*72];   // [l][c], c-granule swizzled by (l>>4)&7
  __shared__ ushort Xl[128*72];
  __shared__ ushort Nh[64*72];
  __shared__ ushort Nl2[64*72];
  __shared__ float a2l[64], el[64];
  const int b = blockIdx.y, lc2 = blockIdx.x;
  const int t = threadIdx.x;
  const int chs = t>>3, qs = t&7;
  const float* xw = x + (size_t)b*TC*TL + (size_t)lc2*256;
  float4 rgv[4];
  #pragma unroll
  for (int i=0;i<4;++i)
    rgv[i] = *(const float4*)(xw + (size_t)chs*TL + qs*16 + 4*i);
  if (t<64){
    const float mu = ws[WS_STATS+128+t]*INV_BL;
    const float var2 = ws[WS_STATS+192+t]*INV_BL - mu*mu;
    const float a2 = g2[t]*rsqrtf(var2 + EPSV);
    a2l[t] = a2;
    el[t] = b2[t] - a2*mu;
  }
  {
    const float* Nsrc = ws + WS_N + b*4096;
    #pragma unroll
    for (int r=0;r<8;++r){
      const int e = t + 512*r;
      const int o = e>>6, c = e&63;
      const float nv = Nsrc[e];
      const ushort h = bf16rne(nv);
      Nh[o*72 + c] = h;
      Nl2[o*72 + c] = bf16rne(nv - __uint_as_float(((uint)h)<<16));
    }
  }
  const int w = __builtin_amdgcn_readfirstlane(t >> 6);
  const int lane = t & 63;
  const int orow = lane & 15, gq = lane >> 4;
  const int lrow = w*16 + orow;
  for (int win=0; win<2; ++win){
    #pragma unroll
    for (int i=0;i<4;++i){
      const float fv[4] = {rgv[i].x, rgv[i].y, rgv[i].z, rgv[i].w};
      #pragma unroll
      for (int j=0;j<4;++j){
        const int l = qs*16 + 4*i + j;
        const int pos = 8*((chs>>3) ^ ((l>>4)&7)) + (chs&7);
        const ushort h = bf16rne(fv[j]);
        Xh[l*72 + pos] = h;
        Xl[l*72 + pos] = bf16rne(fv[j] - __uint_as_float(((uint)h)<<16));
      }
    }
    __syncthreads();
    if (win==0){
      #pragma unroll
      for (int i=0;i<4;++i)
        rgv[i] = *(const float4*)(xw + 128 + (size_t)chs*TL + qs*16 + 4*i);
    }
    f32x4 acc[4];
    #pragma unroll
    for (int i=0;i<4;++i){ acc[i][0]=0.f; acc[i][1]=0.f; acc[i][2]=0.f; acc[i][3]=0.f; }
    #pragma unroll
    for (int ks=0; ks<2; ++ks){
      const int g = ks*4 + gq;
      const int xoff = lrow*72 + 8*(g ^ w);
      const short8v bh = *(const short8v*)&Xh[xoff];
      const short8v bl = *(const short8v*)&Xl[xoff];
      const int cb = g*8;
      #pragma unroll
      for (int ot=0; ot<4; ++ot){
        const short8v ah = *(const short8v*)&Nh[(ot*16+orow)*72 + cb];
        const short8v al = *(const short8v*)&Nl2[(ot*16+orow)*72 + cb];
        acc[ot] = __builtin_amdgcn_mfma_f32_16x16x32_bf16(ah, bh, acc[ot], 0, 0, 0);
        acc[ot] = __builtin_amdgcn_mfma_f32_16x16x32_bf16(ah, bl, acc[ot], 0, 0, 0);
        acc[ot] = __builtin_amdgcn_mfma_f32_16x16x32_bf16(al, bh, acc[ot], 0, 0, 0);
        acc[ot] = __builtin_amdgcn_mfma_f32_16x16x32_bf16(al, bl, acc[ot], 0, 0, 0);
      }
    }
    const int l = lc2*256 + win*128 + w*16 + orow;
    #pragma unroll
    for (int ot=0; ot<4; ++ot){
      #pragma unroll
      for (int r=0;r<4;++r){
        const int o = ot*16 + gq*4 + r;
        const float v = fmaxf(fmaf(a2l[o], acc[ot][r], el[o]), 0.f);
        out[(size_t)(b*TC + o)*TL + l] = v;
      }
    }
    if (win==0) __syncthreads();
  }
}

extern "C" void kernel_launch(void* const* d_in, const int* in_sizes, int n_in,
                              void* d_out, int out_size, void* d_ws, size_t ws_size,
                              hipStream_t stream){
  const float* x  = (const float*)d_in[0];
  const float* wk = (const float*)d_in[1];
  const float* wq = (const float*)d_in[2];
  const float* wv = (const float*)d_in[3];
  const float* wc = (const float*)d_in[4];
  const float* g1 = (const float*)d_in[5];
  /* b1 (d_in[6]) provably cancels through BN2 mean-subtraction */
  const float* wl = (const float*)d_in[7];
  const float* g2 = (const float*)d_in[8];
  const float* b2 = (const float*)d_in[9];
  float* out = (float*)d_out;
  float* ws  = (float*)d_ws;

  k1_gram    <<<dim3(32,16), 256, 0, stream>>>(x, ws);
  kA1        <<<dim3(16,16), 256, 0, stream>>>(wk, ws);
  kA2        <<<dim3(16,16), 256, 0, stream>>>(wq, ws);
  kb12       <<<dim3(16,16), 256, 0, stream>>>(wv, ws);
  kc_mpart   <<<dim3(16,16), 256, 0, stream>>>(wc, ws);
  kd_stats1  <<<dim3(16,16), 256, 0, stream>>>(ws);
  ke_n_stats2<<<dim3(16,16), 256, 0, stream>>>(wl, g1, ws);
  k3_out     <<<dim3(32,16), 512, 0, stream>>>(x, g2, b2, ws, out);
}

// Round 23
// 86.548 us; speedup vs baseline: 1.0112x; 1.0112x over previous
//
#include <hip/hip_runtime.h>
#include <math.h>

#define TB 16
#define TL 8192
#define TC 64

constexpr float INV_BL = 1.0f / (16.0f * 8192.0f);
constexpr float EPSV = 1e-5f;
constexpr float INV_SQRT_H = 0.17677669529663687f; // 1/sqrt(32)

// workspace offsets (floats) — ws is 256 MiB
#define WS_G      0        /* [16][64][64] */
#define WS_SX     65536    /* [16][64] */
#define WS_STATS  66560    /* s1[64] d1[64] s2[64] d2[64] */
#define WS_M      66816    /* [16][64][64] */
#define WS_N      132352   /* [16][64][64] */
#define WS_S1T    197888   /* [16][64][256] -> ends 460032 */
#define WS_V1P    460032   /* [16][16jp][256i][64c] -> ends 4654336 */
#define WS_GPART  4654336  /* [16][32][4096] -> ends 6751488 */
#define WS_SXPART 6751488  /* [16][32][64] -> ends 6784256 */
#define WS_MPART  6784256  /* [16][16][4096] -> ends 7832832 */
#define WS_WKT    7832832  /* wk^T [64][256] -> ends 7849216 */

typedef __attribute__((ext_vector_type(8))) short short8v;  // 8 bf16 (4 VGPRs)
typedef __attribute__((ext_vector_type(4))) float f32x4;    // MFMA C/D

__device__ __forceinline__ ushort bf16rne(float f){
  uint u = __float_as_uint(f);
  u += 0x7FFF + ((u >> 16) & 1);
  return (ushort)(u >> 16);
}

__device__ __forceinline__ int fraddr(int ch, int g){
  return ch*128 + 8*(g ^ (ch & 7));
}

// ---------------- K1 v8: MFMA Gram, 2 subtiles/block with T14 prefetch ----------------
// grid (32 chunk, 16 b), 256 threads = 4 waves. K=256 per block (2 x 128-l subtiles).
__global__ __launch_bounds__(256) void k1_gram(const float* __restrict__ x,
                                               float* __restrict__ ws){
  __shared__ ushort Xh[64*128];
  __shared__ ushort Xl[64*128];
  const int b = blockIdx.y, chunk = blockIdx.x;
  const int t = threadIdx.x;
  const int lane = t & 63;
  const int w = __builtin_amdgcn_readfirstlane(t >> 6);  // wave 0..3
  const float* xb = x + (size_t)b*TC*TL + (size_t)chunk*256;
  const int ch = t >> 2, q = t & 3;
  float sx = 0.f;
  const int rA = w*16 + (lane & 15);
  const int rB = lane & 15;
  const int gq = lane >> 4;
  f32x4 acc0={0.f,0.f,0.f,0.f}, acc1={0.f,0.f,0.f,0.f},
        acc2={0.f,0.f,0.f,0.f}, acc3={0.f,0.f,0.f,0.f};
  float4 rgv[8];
  #pragma unroll
  for (int gg=0; gg<4; ++gg){
    rgv[2*gg]   = *(const float4*)(xb + ch*TL + q*32 + 8*gg);
    rgv[2*gg+1] = *(const float4*)(xb + ch*TL + q*32 + 8*gg + 4);
  }
  #pragma unroll
  for (int gg=0; gg<4; ++gg){
    const float4 v0 = rgv[2*gg], v1 = rgv[2*gg+1];
    const float ff[8] = {v0.x,v0.y,v0.z,v0.w,v1.x,v1.y,v1.z,v1.w};
    union { short8v v; ushort u[8]; } hh, ll;
    #pragma unroll
    for (int i=0;i<8;++i){
      sx += ff[i];
      const ushort hv = bf16rne(ff[i]);
      hh.u[i] = hv;
      ll.u[i] = bf16rne(ff[i] - __uint_as_float(((uint)hv)<<16));
    }
    const int g = q*4 + gg;
    const int wa = ch*128 + 8*(g ^ (ch & 7));
    *(short8v*)&Xh[wa] = hh.v;
    *(short8v*)&Xl[wa] = ll.v;
  }
  __syncthreads();
  float4 rg2[8];
  #pragma unroll
  for (int gg=0; gg<4; ++gg){
    rg2[2*gg]   = *(const float4*)(xb + ch*TL + 128 + q*32 + 8*gg);
    rg2[2*gg+1] = *(const float4*)(xb + ch*TL + 128 + q*32 + 8*gg + 4);
  }
  #pragma unroll
  for (int kk=0; kk<4; ++kk){
    const int g = kk*4 + gq;
    const short8v Ah = *(const short8v*)&Xh[fraddr(rA, g)];
    const short8v Al = *(const short8v*)&Xl[fraddr(rA, g)];
    const short8v Bh0 = *(const short8v*)&Xh[fraddr(rB,      g)];
    const short8v Bl0 = *(const short8v*)&Xl[fraddr(rB,      g)];
    const short8v Bh1 = *(const short8v*)&Xh[fraddr(rB + 16, g)];
    const short8v Bl1 = *(const short8v*)&Xl[fraddr(rB + 16, g)];
    const short8v Bh2 = *(const short8v*)&Xh[fraddr(rB + 32, g)];
    const short8v Bl2 = *(const short8v*)&Xl[fraddr(rB + 32, g)];
    const short8v Bh3 = *(const short8v*)&Xh[fraddr(rB + 48, g)];
    const short8v Bl3 = *(const short8v*)&Xl[fraddr(rB + 48, g)];
    acc0 = __builtin_amdgcn_mfma_f32_16x16x32_bf16(Ah, Bh0, acc0, 0, 0, 0);
    acc0 = __builtin_amdgcn_mfma_f32_16x16x32_bf16(Ah, Bl0, acc0, 0, 0, 0);
    acc0 = __builtin_amdgcn_mfma_f32_16x16x32_bf16(Al, Bh0, acc0, 0, 0, 0);
    acc0 = __builtin_amdgcn_mfma_f32_16x16x32_bf16(Al, Bl0, acc0, 0, 0, 0);
    acc1 = __builtin_amdgcn_mfma_f32_16x16x32_bf16(Ah, Bh1, acc1, 0, 0, 0);
    acc1 = __builtin_amdgcn_mfma_f32_16x16x32_bf16(Ah, Bl1, acc1, 0, 0, 0);
    acc1 = __builtin_amdgcn_mfma_f32_16x16x32_bf16(Al, Bh1, acc1, 0, 0, 0);
    acc1 = __builtin_amdgcn_mfma_f32_16x16x32_bf16(Al, Bl1, acc1, 0, 0, 0);
    acc2 = __builtin_amdgcn_mfma_f32_16x16x32_bf16(Ah, Bh2, acc2, 0, 0, 0);
    acc2 = __builtin_amdgcn_mfma_f32_16x16x32_bf16(Ah, Bl2, acc2, 0, 0, 0);
    acc2 = __builtin_amdgcn_mfma_f32_16x16x32_bf16(Al, Bh2, acc2, 0, 0, 0);
    acc2 = __builtin_amdgcn_mfma_f32_16x16x32_bf16(Al, Bl2, acc2, 0, 0, 0);
    acc3 = __builtin_amdgcn_mfma_f32_16x16x32_bf16(Ah, Bh3, acc3, 0, 0, 0);
    acc3 = __builtin_amdgcn_mfma_f32_16x16x32_bf16(Ah, Bl3, acc3, 0, 0, 0);
    acc3 = __builtin_amdgcn_mfma_f32_16x16x32_bf16(Al, Bh3, acc3, 0, 0, 0);
    acc3 = __builtin_amdgcn_mfma_f32_16x16x32_bf16(Al, Bl3, acc3, 0, 0, 0);
  }
  __syncthreads();
  #pragma unroll
  for (int gg=0; gg<4; ++gg){
    const float4 v0 = rg2[2*gg], v1 = rg2[2*gg+1];
    const float ff[8] = {v0.x,v0.y,v0.z,v0.w,v1.x,v1.y,v1.z,v1.w};
    union { short8v v; ushort u[8]; } hh, ll;
    #pragma unroll
    for (int i=0;i<8;++i){
      sx += ff[i];
      const ushort hv = bf16rne(ff[i]);
      hh.u[i] = hv;
      ll.u[i] = bf16rne(ff[i] - __uint_as_float(((uint)hv)<<16));
    }
    const int g = q*4 + gg;
    const int wa = ch*128 + 8*(g ^ (ch & 7));
    *(short8v*)&Xh[wa] = hh.v;
    *(short8v*)&Xl[wa] = ll.v;
  }
  __syncthreads();
  #pragma unroll
  for (int kk=0; kk<4; ++kk){
    const int g = kk*4 + gq;
    const short8v Ah = *(const short8v*)&Xh[fraddr(rA, g)];
    const short8v Al = *(const short8v*)&Xl[fraddr(rA, g)];
    const short8v Bh0 = *(const short8v*)&Xh[fraddr(rB,      g)];
    const short8v Bl0 = *(const short8v*)&Xl[fraddr(rB,      g)];
    const short8v Bh1 = *(const short8v*)&Xh[fraddr(rB + 16, g)];
    const short8v Bl1 = *(const short8v*)&Xl[fraddr(rB + 16, g)];
    const short8v Bh2 = *(const short8v*)&Xh[fraddr(rB + 32, g)];
    const short8v Bl2 = *(const short8v*)&Xl[fraddr(rB + 32, g)];
    const short8v Bh3 = *(const short8v*)&Xh[fraddr(rB + 48, g)];
    const short8v Bl3 = *(const short8v*)&Xl[fraddr(rB + 48, g)];
    acc0 = __builtin_amdgcn_mfma_f32_16x16x32_bf16(Ah, Bh0, acc0, 0, 0, 0);
    acc0 = __builtin_amdgcn_mfma_f32_16x16x32_bf16(Ah, Bl0, acc0, 0, 0, 0);
    acc0 = __builtin_amdgcn_mfma_f32_16x16x32_bf16(Al, Bh0, acc0, 0, 0, 0);
    acc0 = __builtin_amdgcn_mfma_f32_16x16x32_bf16(Al, Bl0, acc0, 0, 0, 0);
    acc1 = __builtin_amdgcn_mfma_f32_16x16x32_bf16(Ah, Bh1, acc1, 0, 0, 0);
    acc1 = __builtin_amdgcn_mfma_f32_16x16x32_bf16(Ah, Bl1, acc1, 0, 0, 0);
    acc1 = __builtin_amdgcn_mfma_f32_16x16x32_bf16(Al, Bh1, acc1, 0, 0, 0);
    acc1 = __builtin_amdgcn_mfma_f32_16x16x32_bf16(Al, Bl1, acc1, 0, 0, 0);
    acc2 = __builtin_amdgcn_mfma_f32_16x16x32_bf16(Ah, Bh2, acc2, 0, 0, 0);
    acc2 = __builtin_amdgcn_mfma_f32_16x16x32_bf16(Ah, Bl2, acc2, 0, 0, 0);
    acc2 = __builtin_amdgcn_mfma_f32_16x16x32_bf16(Al, Bh2, acc2, 0, 0, 0);
    acc2 = __builtin_amdgcn_mfma_f32_16x16x32_bf16(Al, Bl2, acc2, 0, 0, 0);
    acc3 = __builtin_amdgcn_mfma_f32_16x16x32_bf16(Ah, Bh3, acc3, 0, 0, 0);
    acc3 = __builtin_amdgcn_mfma_f32_16x16x32_bf16(Ah, Bl3, acc3, 0, 0, 0);
    acc3 = __builtin_amdgcn_mfma_f32_16x16x32_bf16(Al, Bh3, acc3, 0, 0, 0);
    acc3 = __builtin_amdgcn_mfma_f32_16x16x32_bf16(Al, Bl3, acc3, 0, 0, 0);
  }
  float* Gp = ws + WS_GPART + (size_t)(b*32 + chunk)*4096;
  const int col = lane & 15, rq = lane >> 4;
  #pragma unroll
  for (int r=0;r<4;++r){
    const int row = (w*16 + rq*4 + r)*64;
    Gp[row +  0 + col] = acc0[r];
    Gp[row + 16 + col] = acc1[r];
    Gp[row + 32 + col] = acc2[r];
    Gp[row + 48 + col] = acc3[r];
  }
  sx += __shfl_xor(sx, 1, 4);
  sx += __shfl_xor(sx, 2, 4);
  if (q == 0){
    ws[WS_SXPART + (b*32+chunk)*64 + ch] = sx;
  }
}

// ---------------- KA1: coalesced G/Sx reduce (32 partials) + STATS zero + wk^T ----------------
__global__ __launch_bounds__(256) void kA1(const float* __restrict__ wk,
                                           float* __restrict__ ws){
  const int p = blockIdx.x, b = blockIdx.y;
  const int t = threadIdx.x;
  const float* Gp = ws + WS_GPART + (size_t)b*32*4096 + p*256 + t;
  float s = 0.f;
  #pragma unroll 8
  for (int ch=0; ch<32; ++ch) s += Gp[(size_t)ch*4096];
  ws[WS_G + b*4096 + p*256 + t] = s;
  if (p==0 && t<64){
    float sv = 0.f;
    #pragma unroll 8
    for (int ch=0; ch<32; ++ch) sv += ws[WS_SXPART + (b*32+ch)*64 + t];
    ws[WS_SX + b*64 + t] = sv;
  }
  if (p==0 && b==0) ws[WS_STATS + t] = 0.f;
  if (b==0){
    const int j = 16*p + (t>>4), k0 = (t&15)*4;
    const float4 v = *(const float4*)(wk + j*64 + k0);
    ws[WS_WKT + (k0+0)*256 + j] = v.x;
    ws[WS_WKT + (k0+1)*256 + j] = v.y;
    ws[WS_WKT + (k0+2)*256 + j] = v.z;
    ws[WS_WKT + (k0+3)*256 + j] = v.w;
  }
}

// ---------------- KA2 v2: S1^T = (wq G)^T, 256 blocks (R19-proven) ----------------
__global__ __launch_bounds__(256) void kA2(const float* __restrict__ wq,
                                           float* __restrict__ ws){
  __shared__ float Gt[64*68];
  const int b = blockIdx.y, iblk = blockIdx.x;
  const int t = threadIdx.x;
  const float* G = ws + WS_G + b*4096;
  #pragma unroll
  for (int r=0;r<4;++r){
    const int idx = r*1024 + t*4;
    *(float4*)&Gt[(idx>>6)*68 + (idx&63)] = *(const float4*)(G + idx);
  }
  __syncthreads();
  const int il = t>>4, cq = t&15;
  const int i = iblk*16 + il;
  const float* wqr = wq + i*64;
  float4 a0={0,0,0,0};
  #pragma unroll 8
  for (int k=0;k<64;++k){
    const float a = wqr[k];
    const float4 g0 = *(const float4*)&Gt[k*68 + cq*4];
    a0.x=fmaf(a,g0.x,a0.x); a0.y=fmaf(a,g0.y,a0.y); a0.z=fmaf(a,g0.z,a0.z); a0.w=fmaf(a,g0.w,a0.w);
  }
  float* S1T = ws + WS_S1T + b*16384;
  S1T[(cq*4+0)*256 + i]=a0.x;
  S1T[(cq*4+1)*256 + i]=a0.y;
  S1T[(cq*4+2)*256 + i]=a0.z;
  S1T[(cq*4+3)*256 + i]=a0.w;
}

// ---------------- KB12 v2: scores (wkT s_loads) + softmax + PV [row][c] (R19-proven) ----------------
__global__ __launch_bounds__(256) void kb12(const float* __restrict__ wv,
                                            float* __restrict__ ws){
  __shared__ float scl[256*17];
  __shared__ float pstat[256];
  __shared__ float fstat[32];
  const int b = blockIdx.y, jp = blockIdx.x;
  const int j0 = jp*16;
  const int t = threadIdx.x;
  const float* S1Tb = ws + WS_S1T + b*16384;
  const float* wkT = ws + WS_WKT;
  float sc[16];
  #pragma unroll
  for (int jj=0;jj<16;++jj) sc[jj]=0.f;
  #pragma unroll 4
  for (int k=0;k<64;++k){
    const float s1 = S1Tb[k*256 + t];
    const float4 w0 = *(const float4*)(wkT + k*256 + j0);
    const float4 w1 = *(const float4*)(wkT + k*256 + j0 + 4);
    const float4 w2 = *(const float4*)(wkT + k*256 + j0 + 8);
    const float4 w3 = *(const float4*)(wkT + k*256 + j0 + 12);
    sc[ 0]=fmaf(w0.x,s1,sc[ 0]); sc[ 1]=fmaf(w0.y,s1,sc[ 1]); sc[ 2]=fmaf(w0.z,s1,sc[ 2]); sc[ 3]=fmaf(w0.w,s1,sc[ 3]);
    sc[ 4]=fmaf(w1.x,s1,sc[ 4]); sc[ 5]=fmaf(w1.y,s1,sc[ 5]); sc[ 6]=fmaf(w1.z,s1,sc[ 6]); sc[ 7]=fmaf(w1.w,s1,sc[ 7]);
    sc[ 8]=fmaf(w2.x,s1,sc[ 8]); sc[ 9]=fmaf(w2.y,s1,sc[ 9]); sc[10]=fmaf(w2.z,s1,sc[10]); sc[11]=fmaf(w2.w,s1,sc[11]);
    sc[12]=fmaf(w3.x,s1,sc[12]); sc[13]=fmaf(w3.y,s1,sc[13]); sc[14]=fmaf(w3.z,s1,sc[14]); sc[15]=fmaf(w3.w,s1,sc[15]);
  }
  #pragma unroll
  for (int jj=0;jj<16;++jj) scl[t*17+jj] = sc[jj];
  __syncthreads();
  const int col = t&15, ig = t>>4;
  {
    float m = -3.0e38f;
    #pragma unroll
    for (int q=0;q<16;++q) m = fmaxf(m, scl[(ig*16+q)*17 + col]);
    pstat[ig*16+col] = m;
  }
  __syncthreads();
  if (t<16){
    float m = -3.0e38f;
    #pragma unroll
    for (int q=0;q<16;++q) m = fmaxf(m, pstat[q*16+t]);
    fstat[t] = m;
  }
  __syncthreads();
  {
    const float mj = fstat[col];
    float s = 0.f;
    #pragma unroll
    for (int q=0;q<16;++q) s += __expf(scl[(ig*16+q)*17 + col] - mj);
    pstat[ig*16+col] = s;
  }
  __syncthreads();
  if (t<16){
    float s = 0.f;
    #pragma unroll
    for (int q=0;q<16;++q) s += pstat[q*16+t];
    fstat[16+t] = 1.f/s;
  }
  __syncthreads();
  #pragma unroll
  for (int jj=0;jj<16;++jj)
    sc[jj] = __expf(sc[jj] - fstat[jj]) * fstat[16+jj];
  float* Vp = ws + WS_V1P + (size_t)(b*16 + jp)*16384 + t*64;
  #pragma unroll
  for (int cb=0; cb<4; ++cb){
    float acc[16];
    #pragma unroll
    for (int cc=0;cc<16;++cc) acc[cc]=0.f;
    #pragma unroll
    for (int jj=0;jj<16;++jj){
      const float p = sc[jj];
      const float* wvr = wv + (j0+jj)*64 + cb*16;
      #pragma unroll
      for (int cc=0;cc<16;++cc)
        acc[cc] = fmaf(p, wvr[cc], acc[cc]);
    }
    #pragma unroll
    for (int g=0; g<4; ++g){
      float4 v; v.x=acc[4*g]; v.y=acc[4*g+1]; v.z=acc[4*g+2]; v.w=acc[4*g+3];
      *(float4*)&Vp[cb*16 + 4*g] = v;
    }
  }
}

// ---------------- KC v3: sum V1 partials + M K-partials (R19-proven) ----------------
__global__ __launch_bounds__(256) void kc_mpart(const float* __restrict__ wc,
                                                float* __restrict__ ws){
  __shared__ float V1l[16*65];
  const int b = blockIdx.y, kq = blockIdx.x;
  const int t = threadIdx.x;
  #pragma unroll
  for (int r=0;r<4;++r){
    const int e = t + 256*r;
    const int c = e & 63, il = e >> 6;
    const float* Vp = ws + WS_V1P + (size_t)b*16*16384 + (kq*16+il)*64 + c;
    float s = 0.f;
    #pragma unroll
    for (int jp=0;jp<16;++jp) s += Vp[jp*16384];
    V1l[il*65 + c] = s * INV_SQRT_H;
  }
  __syncthreads();
  const int c = t & 63;
  const int og = __builtin_amdgcn_readfirstlane(t >> 6);
  float acc[16];
  #pragma unroll
  for (int oo=0;oo<16;++oo) acc[oo]=0.f;
  #pragma unroll
  for (int il=0; il<16; ++il){
    const float v = V1l[il*65 + c];
    const float* wcr = wc + (og*16)*256 + kq*16 + il;
    #pragma unroll
    for (int oo=0;oo<16;++oo)
      acc[oo] = fmaf(wcr[oo*256], v, acc[oo]);
  }
  float* Mp = ws + WS_MPART + (size_t)(b*16 + kq)*4096;
  #pragma unroll
  for (int oo=0;oo<16;++oo)
    Mp[(og*16+oo)*64 + c] = acc[oo];
}

// ---------------- KD v2: M rows + BN1 stats (R12-proven) ----------------
__global__ __launch_bounds__(256) void kd_stats1(float* __restrict__ ws){
  __shared__ float Msub[4*65];
  __shared__ float Gl[64*67];
  __shared__ float Sxl[64];
  const int b = blockIdx.y, oq = blockIdx.x;
  const int t = threadIdx.x;
  const int o = t >> 6, lane = t & 63;
  const int row = oq*4 + o;
  {
    const float* Mp = ws + WS_MPART + (size_t)b*16*4096 + row*64 + lane;
    float s = 0.f;
    #pragma unroll
    for (int kq=0;kq<16;++kq) s += Mp[kq*4096];
    ws[WS_M + b*4096 + row*64 + lane] = s;
    Msub[o*65 + lane] = s;
  }
  #pragma unroll
  for (int r=0;r<16;++r){
    const int e = t + 256*r;
    Gl[(e>>6)*67 + (e&63)] = ws[WS_G + b*4096 + e];
  }
  if (t<64) Sxl[t] = ws[WS_SX + b*64 + t];
  __syncthreads();
  float sk = 0.f;
  #pragma unroll 4
  for (int c=0;c<64;++c) sk = fmaf(Gl[lane*67+c], Msub[o*65+c], sk);
  float d = Msub[o*65 + lane] * sk;
  float s1 = Msub[o*65 + lane] * Sxl[lane];
  #pragma unroll
  for (int off=1; off<64; off<<=1){
    d  += __shfl_xor(d,  off);
    s1 += __shfl_xor(s1, off);
  }
  if (lane==0){
    atomicAdd(&ws[WS_STATS + row], s1);
    atomicAdd(&ws[WS_STATS + 64 + row], d);
  }
}

// ---------------- KE v2: N rows + BN2 stats (R12-proven) ----------------
__global__ __launch_bounds__(256) void ke_n_stats2(const float* __restrict__ wl,
                                                   const float* __restrict__ g1,
                                                   float* __restrict__ ws){
  __shared__ float Ml[64*65];
  __shared__ float Gl[64*67];
  __shared__ float Nsub[4*65];
  __shared__ float Sxl[64], a1l[64];
  const int b = blockIdx.y, oq = blockIdx.x;
  const int t = threadIdx.x;
  const int o = t >> 6, lane = t & 63;
  const int row = oq*4 + o;
  if (t<64){
    const float mean1 = ws[WS_STATS+t]*INV_BL;
    const float var1 = ws[WS_STATS+64+t]*INV_BL - mean1*mean1;
    a1l[t] = g1[t]*rsqrtf(var1 + EPSV);
    Sxl[t] = ws[WS_SX + b*64 + t];
  }
  #pragma unroll
  for (int r=0;r<16;++r){
    const int e = t + 256*r;
    Ml[(e>>6)*65 + (e&63)] = ws[WS_M + b*4096 + e];
    Gl[(e>>6)*67 + (e&63)] = ws[WS_G + b*4096 + e];
  }
  __syncthreads();
  float acc = 0.f;
  #pragma unroll 4
  for (int k=0;k<64;++k){
    const float wk_ = wl[row*64 + k] * a1l[k];
    acc = fmaf(wk_, Ml[k*65 + lane], acc);
  }
  const float nv = acc + wl[row*64 + lane];
  ws[WS_N + b*4096 + row*64 + lane] = nv;
  Nsub[o*65 + lane] = nv;
  __syncthreads();
  float sk = 0.f;
  #pragma unroll 4
  for (int c=0;c<64;++c) sk = fmaf(Gl[lane*67+c], Nsub[o*65+c], sk);
  float d = Nsub[o*65 + lane] * sk;
  float s2 = Nsub[o*65 + lane] * Sxl[lane];
  #pragma unroll
  for (int off=1; off<64; off<<=1){
    d  += __shfl_xor(d,  off);
    s2 += __shfl_xor(s2, off);
  }
  if (lane==0){
    atomicAdd(&ws[WS_STATS + 128 + row], s2);
    atomicAdd(&ws[WS_STATS + 192 + row], d);
  }
}

// ---------------- K3 v7: MFMA out-GEMM, 2 windows/block with T14 prefetch ----------------
// grid (32 lc2, 16 b), 512 threads. N staged once; win1 loads hide under win0 MFMA+stores.
__global__ __launch_bounds__(512) void k3_out(const float* __restrict__ x,
                                              const float* __restrict__ g2,
                                              const float* __restrict__ b2,
                                              const float* __restrict__ ws,
                                              float* __restrict__ out){
  __shared__ ushort Xh[128*72];   // [l][c], c-granule swizzled by (l>>4)&7
  __shared__ ushort Xl[128*72];
  __shared__ ushort Nh[64*72];
  __shared__ ushort Nl2[64*72];
  __shared__ float a2l[64], el[64];
  const int b = blockIdx.y, lc2 = blockIdx.x;
  const int t = threadIdx.x;
  const int chs = t>>3, qs = t&7;
  const float* xw = x + (size_t)b*TC*TL + (size_t)lc2*256;
  float4 rgv[4];
  #pragma unroll
  for (int i=0;i<4;++i)
    rgv[i] = *(const float4*)(xw + (size_t)chs*TL + qs*16 + 4*i);
  if (t<64){
    const float mu = ws[WS_STATS+128+t]*INV_BL;
    const float var2 = ws[WS_STATS+192+t]*INV_BL - mu*mu;
    const float a2 = g2[t]*rsqrtf(var2 + EPSV);
    a2l[t] = a2;
    el[t] = b2[t] - a2*mu;
  }
  {
    const float* Nsrc = ws + WS_N + b*4096;
    #pragma unroll
    for (int r=0;r<8;++r){
      const int e = t + 512*r;
      const int o = e>>6, c = e&63;
      const float nv = Nsrc[e];
      const ushort h = bf16rne(nv);
      Nh[o*72 + c] = h;
      Nl2[o*72 + c] = bf16rne(nv - __uint_as_float(((uint)h)<<16));
    }
  }
  const int w = __builtin_amdgcn_readfirstlane(t >> 6);
  const int lane = t & 63;
  const int orow = lane & 15, gq = lane >> 4;
  const int lrow = w*16 + orow;
  for (int win=0; win<2; ++win){
    #pragma unroll
    for (int i=0;i<4;++i){
      const float fv[4] = {rgv[i].x, rgv[i].y, rgv[i].z, rgv[i].w};
      #pragma unroll
      for (int j=0;j<4;++j){
        const int l = qs*16 + 4*i + j;
        const int pos = 8*((chs>>3) ^ ((l>>4)&7)) + (chs&7);
        const ushort h = bf16rne(fv[j]);
        Xh[l*72 + pos] = h;
        Xl[l*72 + pos] = bf16rne(fv[j] - __uint_as_float(((uint)h)<<16));
      }
    }
    __syncthreads();
    if (win==0){
      #pragma unroll
      for (int i=0;i<4;++i)
        rgv[i] = *(const float4*)(xw + 128 + (size_t)chs*TL + qs*16 + 4*i);
    }
    f32x4 acc[4];
    #pragma unroll
    for (int i=0;i<4;++i){ acc[i][0]=0.f; acc[i][1]=0.f; acc[i][2]=0.f; acc[i][3]=0.f; }
    #pragma unroll
    for (int ks=0; ks<2; ++ks){
      const int g = ks*4 + gq;
      const int xoff = lrow*72 + 8*(g ^ w);
      const short8v bh = *(const short8v*)&Xh[xoff];
      const short8v bl = *(const short8v*)&Xl[xoff];
      const int cb = g*8;
      #pragma unroll
      for (int ot=0; ot<4; ++ot){
        const short8v ah = *(const short8v*)&Nh[(ot*16+orow)*72 + cb];
        const short8v al = *(const short8v*)&Nl2[(ot*16+orow)*72 + cb];
        acc[ot] = __builtin_amdgcn_mfma_f32_16x16x32_bf16(ah, bh, acc[ot], 0, 0, 0);
        acc[ot] = __builtin_amdgcn_mfma_f32_16x16x32_bf16(ah, bl, acc[ot], 0, 0, 0);
        acc[ot] = __builtin_amdgcn_mfma_f32_16x16x32_bf16(al, bh, acc[ot], 0, 0, 0);
        acc[ot] = __builtin_amdgcn_mfma_f32_16x16x32_bf16(al, bl, acc[ot], 0, 0, 0);
      }
    }
    const int l = lc2*256 + win*128 + w*16 + orow;
    #pragma unroll
    for (int ot=0; ot<4; ++ot){
      #pragma unroll
      for (int r=0;r<4;++r){
        const int o = ot*16 + gq*4 + r;
        const float v = fmaxf(fmaf(a2l[o], acc[ot][r], el[o]), 0.f);
        out[(size_t)(b*TC + o)*TL + l] = v;
      }
    }
    if (win==0) __syncthreads();
  }
}

extern "C" void kernel_launch(void* const* d_in, const int* in_sizes, int n_in,
                              void* d_out, int out_size, void* d_ws, size_t ws_size,
                              hipStream_t stream){
  const float* x  = (const float*)d_in[0];
  const float* wk = (const float*)d_in[1];
  const float* wq = (const float*)d_in[2];
  const float* wv = (const float*)d_in[3];
  const float* wc = (const float*)d_in[4];
  const float* g1 = (const float*)d_in[5];
  /* b1 (d_in[6]) provably cancels through BN2 mean-subtraction */
  const float* wl = (const float*)d_in[7];
  const float* g2 = (const float*)d_in[8];
  const float* b2 = (const float*)d_in[9];
  float* out = (float*)d_out;
  float* ws  = (float*)d_ws;

  k1_gram    <<<dim3(32,16), 256, 0, stream>>>(x, ws);
  kA1        <<<dim3(16,16), 256, 0, stream>>>(wk, ws);
  kA2        <<<dim3(16,16), 256, 0, stream>>>(wq, ws);
  kb12       <<<dim3(16,16), 256, 0, stream>>>(wv, ws);
  kc_mpart   <<<dim3(16,16), 256, 0, stream>>>(wc, ws);
  kd_stats1  <<<dim3(16,16), 256, 0, stream>>>(ws);
  ke_n_stats2<<<dim3(16,16), 256, 0, stream>>>(wl, g1, ws);
  k3_out     <<<dim3(32,16), 512, 0, stream>>>(x, g2, b2, ws, out);
}